// Round 7
// baseline (356.405 us; speedup 1.0000x reference)
//
#include <hip/hip_runtime.h>
#include <hip/hip_bf16.h>

#define DEV __device__ __forceinline__

typedef __attribute__((ext_vector_type(8))) short bf16x8;
typedef __attribute__((ext_vector_type(4))) float f32x4;
typedef unsigned int u32;
typedef unsigned long long u64;

#define VMCNT(n) asm volatile("s_waitcnt vmcnt(" #n ")" ::: "memory")

DEV short f2bf(float f) {
  union { float f; u32 u; } x; x.f = f;
  u32 r = x.u + 0x7fffu + ((x.u >> 16) & 1u);   // RNE
  return (short)(r >> 16);
}

DEV void gload_lds16(const void* g, void* l) {
  __builtin_amdgcn_global_load_lds(
      (const __attribute__((address_space(1))) u32*)g,
      (__attribute__((address_space(3))) u32*)l, 16, 0, 0);
}

// XOR-swizzled fragment read (matches pre-swizzled-source staging). col in shorts.
DEV bf16x8 frag(const short* L, int row, int col) {
  return *(const bf16x8*)&L[row * 64 + (col ^ ((row & 7) << 3))];
}

// ---- staging: rows x 64-short K-slice, linear LDS dest, swizzled global src ----
// A tile: 256 rows (4 loads/thread). B tile: 128 rows (2 loads/thread).
DEV void stageA256(const char* base, int ktb, char* lds, int w, int lane) {
  int r8 = lane >> 3;
  int csw = ((lane & 7) ^ r8) << 4;
#pragma unroll
  for (int l = 0; l < 4; ++l) {
    int c = l * 8 + w;
    gload_lds16(base + (size_t)(c * 8 + r8) * 2048 + ktb + csw, lds + c * 1024);
  }
}
DEV void stageB128(const char* base, int ktb, char* lds, int w, int lane) {
  int r8 = lane >> 3;
  int csw = ((lane & 7) ^ r8) << 4;
#pragma unroll
  for (int l = 0; l < 2; ++l) {
    int c = l * 8 + w;
    gload_lds16(base + (size_t)(c * 8 + r8) * 2048 + ktb + csw, lds + c * 1024);
  }
}

// ---- one K-tile of MFMA work: per-wave 128x32 output, 32 MFMAs ----
DEV void tile_compute(const short* Asb, const short* Bsb, f32x4 acc[8][2],
                      int wm, int wn, int lr, int lg) {
  bf16x8 bfrag[2][2];
#pragma unroll
  for (int ni = 0; ni < 2; ++ni)
#pragma unroll
    for (int ks = 0; ks < 2; ++ks)
      bfrag[ni][ks] = frag(Bsb, wn * 32 + ni * 16 + lr, ks * 32 + lg * 8);
#pragma unroll
  for (int pi = 0; pi < 4; ++pi) {
    bf16x8 af[2][2];
#pragma unroll
    for (int m2 = 0; m2 < 2; ++m2)
#pragma unroll
      for (int ks = 0; ks < 2; ++ks)
        af[m2][ks] = frag(Asb, wm * 128 + (pi * 2 + m2) * 16 + lr, ks * 32 + lg * 8);
    __builtin_amdgcn_s_setprio(1);
#pragma unroll
    for (int m2 = 0; m2 < 2; ++m2)
#pragma unroll
      for (int ni = 0; ni < 2; ++ni)
#pragma unroll
        for (int ks = 0; ks < 2; ++ks)
          acc[pi * 2 + m2][ni] = __builtin_amdgcn_mfma_f32_16x16x32_bf16(
              af[m2][ks], bfrag[ni][ks], acc[pi * 2 + m2][ni], 0, 0, 0);
    __builtin_amdgcn_s_setprio(0);
  }
}

#define ENTRY_SYNC()                          \
  __builtin_amdgcn_sched_barrier(0);          \
  __builtin_amdgcn_s_barrier();               \
  __builtin_amdgcn_sched_barrier(0)

// ---------- fused prologue: aconv (fp32->bf16), wconv4 (transpose), pack_mask ----------
__global__ __launch_bounds__(256) void prologue(
    const float* __restrict__ q, const float* __restrict__ k, const float* __restrict__ v,
    short* __restrict__ qb, short* __restrict__ kb, short* __restrict__ vb,
    const float* __restrict__ W0, const float* __restrict__ W1,
    const float* __restrict__ W2, const float* __restrict__ W3,
    short* __restrict__ WtAll,
    const int* __restrict__ mask, const int* __restrict__ tmask, u64* __restrict__ pk) {
  int bx = blockIdx.x;
  if (bx < 12288) {                       // ---- activation convert ----
    int z = bx >> 12, bi = bx & 4095;
    const float* src = z == 0 ? q : z == 1 ? k : v;
    short* dst = z == 0 ? qb : z == 1 ? kb : vb;
    size_t i = ((size_t)bi * 256 + threadIdx.x) * 8;
    float4 f0 = *(const float4*)(src + i);
    float4 f1 = *(const float4*)(src + i + 4);
    bf16x8 o;
    o[0] = f2bf(f0.x); o[1] = f2bf(f0.y); o[2] = f2bf(f0.z); o[3] = f2bf(f0.w);
    o[4] = f2bf(f1.x); o[5] = f2bf(f1.y); o[6] = f2bf(f1.z); o[7] = f2bf(f1.w);
    *(bf16x8*)(dst + i) = o;
  } else if (bx < 13312) {                // ---- weight convert+transpose ----
    int idx = bx - 12288;
    int z = idx >> 8, rem = idx & 255;
    const float* W = z == 0 ? W0 : z == 1 ? W1 : z == 2 ? W2 : W3;
    short* Wt = WtAll + (size_t)z * 1024 * 1024;
    __shared__ short tile[64][65];
    int k0 = (rem >> 4) * 64, n0 = (rem & 15) * 64;
    int t = threadIdx.x;
    int r = t >> 2, c = (t & 3) * 16;
    const float* src = W + (size_t)(k0 + r) * 1024 + n0 + c;
#pragma unroll
    for (int i = 0; i < 16; i += 4) {
      float4 f = *(const float4*)(src + i);
      tile[r][c + i + 0] = f2bf(f.x);
      tile[r][c + i + 1] = f2bf(f.y);
      tile[r][c + i + 2] = f2bf(f.z);
      tile[r][c + i + 3] = f2bf(f.w);
    }
    __syncthreads();
    bf16x8 v0, v1;
#pragma unroll
    for (int i = 0; i < 8; ++i) v0[i] = tile[c + i][r];
#pragma unroll
    for (int i = 0; i < 8; ++i) v1[i] = tile[c + 8 + i][r];
    short* dst = Wt + (size_t)(n0 + r) * 1024 + k0 + c;
    *(bf16x8*)(dst) = v0;
    *(bf16x8*)(dst + 8) = v1;
  } else {                                // ---- mask packing ----
    int bn = bx - 13312;                  // (b*1024 + n)
    int b = bn >> 10;
    int t = threadIdx.x, w = t >> 6, lane = t & 63;
    const int* tr = tmask + (size_t)bn * 1024;
    const int* mr = mask + b * 1024;
#pragma unroll
    for (int it = 0; it < 4; ++it) {
      int m = it * 256 + w * 64 + lane;
      bool on = (mr[m] != 0) && (tr[m] != 0);
      u64 bits = __ballot(on);
      if (lane == 0) pk[(size_t)bn * 16 + it * 4 + w] = bits;
    }
  }
}

// ---------- vh (B,H,M,D) -> vht (B,H,D,M), bf16 ----------
__global__ __launch_bounds__(256) void vtrans(const short* __restrict__ vh,
                                              short* __restrict__ vht) {
  __shared__ short tile[64][65];
  int m0 = blockIdx.x * 64;
  int bh = blockIdx.y;
  int t = threadIdx.x;
  int r = t >> 2, c = (t & 3) * 16;
  const short* src = vh + ((size_t)bh * 1024 + m0 + r) * 64 + c;
  bf16x8 a0 = *(const bf16x8*)(src);
  bf16x8 a1 = *(const bf16x8*)(src + 8);
#pragma unroll
  for (int i = 0; i < 8; ++i) tile[r][c + i] = a0[i];
#pragma unroll
  for (int i = 0; i < 8; ++i) tile[r][c + 8 + i] = a1[i];
  __syncthreads();
  bf16x8 v0, v1;
#pragma unroll
  for (int i = 0; i < 8; ++i) v0[i] = tile[c + i][r];
#pragma unroll
  for (int i = 0; i < 8; ++i) v1[i] = tile[c + 8 + i][r];
  short* dst = vht + ((size_t)bh * 64 + r) * 1024 + m0 + c;
  *(bf16x8*)dst = v0;
  *(bf16x8*)(dst + 8) = v1;
}

// ---------- QKV projection GEMM: 256x128 tile, 3-buf LDS, counted vmcnt ----------
#define QSCALE 0.18033688011112042f

__global__ __launch_bounds__(512, 2) void gemm_qkv(
    const short* __restrict__ qb, const short* __restrict__ kb, const short* __restrict__ vb,
    const short* __restrict__ WtAll,
    short* __restrict__ qh, short* __restrict__ kh, short* __restrict__ vh) {
  __shared__ __align__(16) short AsAll[3 * 256 * 64];   // 96 KB
  __shared__ __align__(16) short BsAll[3 * 128 * 64];   // 48 KB

  int flat = blockIdx.y * 8 + blockIdx.x;   // 768 blocks
  int nid = (flat & 7) * 96 + (flat >> 3);  // XCD chunking (768 % 8 == 0, bijective)
  int zz = nid >> 8;
  int rr = nid & 255;
  int bm = (rr >> 3) * 256, bn = (rr & 7) * 128;

  const short* A; short* Ch; float cs;
  if (zz == 0)      { A = qb; Ch = qh; cs = QSCALE; }
  else if (zz == 1) { A = kb; Ch = kh; cs = 1.0f; }
  else              { A = vb; Ch = vh; cs = 1.0f; }
  const short* Wt = WtAll + (size_t)zz * 1024 * 1024;

  int tid = threadIdx.x;
  int lane = tid & 63, w = tid >> 6;
  int wm = w >> 2, wn = w & 3;
  int lr = lane & 15, lg = lane >> 4;

  const f32x4 fz = {0.f, 0.f, 0.f, 0.f};
  f32x4 acc[8][2];
#pragma unroll
  for (int i = 0; i < 8; ++i) { acc[i][0] = fz; acc[i][1] = fz; }

  const char* abase = (const char*)A + (size_t)bm * 2048;
  const char* bbase = (const char*)Wt + (size_t)bn * 2048;

  // prologue: stage tiles 0,1 (6 loads each)
  stageA256(abase, 0, (char*)AsAll, w, lane);
  stageB128(bbase, 0, (char*)BsAll, w, lane);
  stageA256(abase, 128, (char*)AsAll + 32768, w, lane);
  stageB128(bbase, 128, (char*)BsAll + 16384, w, lane);

  int cb = 0, sb = 2;   // consume buf, stage buf (tile t+2)
  for (int t = 0; t < 15; ++t) {
    VMCNT(6);           // tile t landed; tile t+1's 6 loads may remain in flight
    ENTRY_SYNC();
    if (t < 14) {
      stageA256(abase, (t + 2) * 128, (char*)AsAll + sb * 32768, w, lane);
      stageB128(bbase, (t + 2) * 128, (char*)BsAll + sb * 16384, w, lane);
    }
    tile_compute(AsAll + cb * 16384, BsAll + cb * 8192, acc, wm, wn, lr, lg);
    cb = (cb == 2) ? 0 : cb + 1;
    sb = (sb == 2) ? 0 : sb + 1;
  }
  VMCNT(0);             // final tile drain
  ENTRY_SYNC();
  tile_compute(AsAll + cb * 16384, BsAll + cb * 8192, acc, wm, wn, lr, lg);

  // epilogue: write (B,H,N,64)
#pragma unroll
  for (int mi = 0; mi < 8; ++mi)
#pragma unroll
    for (int ni = 0; ni < 2; ++ni) {
      int ccol = bn + wn * 32 + ni * 16 + lr;
      int h = ccol >> 6, d = ccol & 63;
#pragma unroll
      for (int j = 0; j < 4; ++j) {
        int r = bm + wm * 128 + mi * 16 + lg * 4 + j;
        int bb = r >> 10, n = r & 1023;
        Ch[(((size_t)bb * 16 + h) * 1024 + n) * 64 + d] = f2bf(acc[mi][ni][j] * cs);
      }
    }
}

// ---------- output GEMM: 256x128 tile, 3-buf LDS, counted vmcnt, fp32 + bias ----------
__global__ __launch_bounds__(512, 2) void gemm_out(
    const short* __restrict__ X, const short* __restrict__ Wot,
    const float* __restrict__ bo, float* __restrict__ out) {
  __shared__ __align__(16) short AsAll[3 * 256 * 64];
  __shared__ __align__(16) short BsAll[3 * 128 * 64];

  int flat = blockIdx.y * 8 + blockIdx.x;   // 256 blocks
  int nid = (flat & 7) * 32 + (flat >> 3);
  int bm = (nid >> 3) * 256, bn = (nid & 7) * 128;

  int tid = threadIdx.x;
  int lane = tid & 63, w = tid >> 6;
  int wm = w >> 2, wn = w & 3;
  int lr = lane & 15, lg = lane >> 4;

  const f32x4 fz = {0.f, 0.f, 0.f, 0.f};
  f32x4 acc[8][2];
#pragma unroll
  for (int i = 0; i < 8; ++i) { acc[i][0] = fz; acc[i][1] = fz; }

  const char* abase = (const char*)X + (size_t)bm * 2048;
  const char* bbase = (const char*)Wot + (size_t)bn * 2048;

  stageA256(abase, 0, (char*)AsAll, w, lane);
  stageB128(bbase, 0, (char*)BsAll, w, lane);
  stageA256(abase, 128, (char*)AsAll + 32768, w, lane);
  stageB128(bbase, 128, (char*)BsAll + 16384, w, lane);

  int cb = 0, sb = 2;
  for (int t = 0; t < 15; ++t) {
    VMCNT(6);
    ENTRY_SYNC();
    if (t < 14) {
      stageA256(abase, (t + 2) * 128, (char*)AsAll + sb * 32768, w, lane);
      stageB128(bbase, (t + 2) * 128, (char*)BsAll + sb * 16384, w, lane);
    }
    tile_compute(AsAll + cb * 16384, BsAll + cb * 8192, acc, wm, wn, lr, lg);
    cb = (cb == 2) ? 0 : cb + 1;
    sb = (sb == 2) ? 0 : sb + 1;
  }
  VMCNT(0);
  ENTRY_SYNC();
  tile_compute(AsAll + cb * 16384, BsAll + cb * 8192, acc, wm, wn, lr, lg);

#pragma unroll
  for (int mi = 0; mi < 8; ++mi)
#pragma unroll
    for (int ni = 0; ni < 2; ++ni) {
      int ccol = bn + wn * 32 + ni * 16 + lr;
      float bias = bo[ccol];
#pragma unroll
      for (int j = 0; j < 4; ++j) {
        int r = bm + wm * 128 + mi * 16 + lg * 4 + j;
        out[(size_t)r * 1024 + ccol] = acc[mi][ni][j] + bias;
      }
    }
}

// ---------- flash attention (unchanged from round 5) ----------
DEV void stage_kv(const char* kbase, const char* vbase, int kv0,
                  short* Ksb, short* Vsb, int w, int lane) {
#pragma unroll
  for (int i = 0; i < 2; ++i) {
    int c = w * 2 + i;
    int row = (lane >> 3);
    int colb = ((lane & 7) ^ row) << 4;          // pre-swizzled source column
    gload_lds16(kbase + (size_t)(kv0 + c * 8 + row) * 128 + colb, (char*)Ksb + c * 1024);
    gload_lds16(vbase + (size_t)(c * 8 + row) * 2048 + kv0 * 2 + colb, (char*)Vsb + c * 1024);
  }
}

__global__ __launch_bounds__(256, 2) void attn(
    const short* __restrict__ qh, const short* __restrict__ kh, const short* __restrict__ vht,
    const u64* __restrict__ pk, short* __restrict__ x) {
  __shared__ __align__(16) short Ks[2][4096];   // [key][d], XOR-swizzled
  __shared__ __align__(16) short Vs[2][4096];   // [d][key], XOR-swizzled
  __shared__ __align__(16) short Ps[2][8192];   // per-subtile [qrow][key], XOR-swizzled

  int flat = blockIdx.y * 8 + blockIdx.x;       // grid (8, 64) = 512 blocks
  int nid = (flat & 7) * 64 + (flat >> 3);      // XCD chunking (bijective: 512 = 8*64)
  int bh = nid >> 2, qp = nid & 3;              // 4 q-pairs (256 rows) per head
  int b = bh >> 4;
  int tid = threadIdx.x, lane = tid & 63, w = tid >> 6;
  int lr = lane & 15, lg = lane >> 4;

  bf16x8 qa[2][2][2];                           // [sub][mi][ks]
#pragma unroll
  for (int sub = 0; sub < 2; ++sub) {
    const short* qb2 = qh + ((size_t)bh * 1024 + qp * 256 + sub * 128 + w * 32) * 64;
#pragma unroll
    for (int mi = 0; mi < 2; ++mi)
#pragma unroll
      for (int ks = 0; ks < 2; ++ks)
        qa[sub][mi][ks] = *(const bf16x8*)(qb2 + (mi * 16 + lr) * 64 + ks * 32 + lg * 8);
  }

  const f32x4 fz = {0.f, 0.f, 0.f, 0.f};
  f32x4 o[2][2][4];
  float psum[2][2][4];
#pragma unroll
  for (int sub = 0; sub < 2; ++sub)
#pragma unroll
    for (int mi = 0; mi < 2; ++mi)
#pragma unroll
      for (int j = 0; j < 4; ++j) { psum[sub][mi][j] = 0.f; o[sub][mi][j] = fz; }

  const char* kbase = (const char*)(kh + (size_t)bh * 65536);
  const char* vbase = (const char*)(vht + (size_t)bh * 65536);
  const u64* pkb = pk + ((size_t)b * 1024 + qp * 256) * 16;

  stage_kv(kbase, vbase, 0, Ks[0], Vs[0], w, lane);
  __syncthreads();
  int cur = 0;

  for (int t = 0; t < 16; ++t) {
    if (t < 15) stage_kv(kbase, vbase, (t + 1) * 64, Ks[cur ^ 1], Vs[cur ^ 1], w, lane);

#pragma unroll
    for (int sub = 0; sub < 2; ++sub) {
      u64 pw[2][4];
#pragma unroll
      for (int mi = 0; mi < 2; ++mi)
#pragma unroll
        for (int j = 0; j < 4; ++j)
          pw[mi][j] = pkb[(sub * 128 + w * 32 + mi * 16 + lg * 4 + j) * 16 + t];

      f32x4 s[2][4];
#pragma unroll
      for (int mi = 0; mi < 2; ++mi)
#pragma unroll
        for (int ni = 0; ni < 4; ++ni) s[mi][ni] = fz;
      __builtin_amdgcn_s_setprio(1);
#pragma unroll
      for (int ks = 0; ks < 2; ++ks) {
        bf16x8 kb2[4];
#pragma unroll
        for (int ni = 0; ni < 4; ++ni)
          kb2[ni] = *(const bf16x8*)&Ks[cur][(ni * 16 + lr) * 64 + ((ks * 32 + lg * 8) ^ ((lr & 7) << 3))];
#pragma unroll
        for (int mi = 0; mi < 2; ++mi)
#pragma unroll
          for (int ni = 0; ni < 4; ++ni)
            s[mi][ni] = __builtin_amdgcn_mfma_f32_16x16x32_bf16(qa[sub][mi][ks], kb2[ni], s[mi][ni], 0, 0, 0);
      }
      __builtin_amdgcn_s_setprio(0);

#pragma unroll
      for (int mi = 0; mi < 2; ++mi)
#pragma unroll
        for (int j = 0; j < 4; ++j) {
          u32 lo = (u32)pw[mi][j], hi = (u32)(pw[mi][j] >> 32);
          int r = w * 32 + mi * 16 + lg * 4 + j;
          int sw = (r & 7) << 3;
          float rs = 0.f;
#pragma unroll
          for (int ni = 0; ni < 4; ++ni) {
            u32 bit = ((ni < 2 ? lo : hi) >> ((ni & 1) * 16 + lr)) & 1u;
            float e = __builtin_amdgcn_exp2f(s[mi][ni][j]);
            float p = bit ? e : 0.f;
            rs += p;
            union { float f; u32 u; } cv; cv.f = p;
            Ps[sub][r * 64 + ((ni * 16 + lr) ^ sw)] = (short)((cv.u + 0x8000u) >> 16);
          }
          psum[sub][mi][j] += rs;
        }

      __builtin_amdgcn_s_setprio(1);
#pragma unroll
      for (int ks = 0; ks < 2; ++ks) {
        bf16x8 pa[2], vb2[4];
#pragma unroll
        for (int mi = 0; mi < 2; ++mi)
          pa[mi] = *(const bf16x8*)&Ps[sub][(w * 32 + mi * 16 + lr) * 64 + ((ks * 32 + lg * 8) ^ ((lr & 7) << 3))];
#pragma unroll
        for (int nd = 0; nd < 4; ++nd)
          vb2[nd] = *(const bf16x8*)&Vs[cur][(nd * 16 + lr) * 64 + ((ks * 32 + lg * 8) ^ ((lr & 7) << 3))];
#pragma unroll
        for (int mi = 0; mi < 2; ++mi)
#pragma unroll
          for (int nd = 0; nd < 4; ++nd)
            o[sub][mi][nd] = __builtin_amdgcn_mfma_f32_16x16x32_bf16(pa[mi], vb2[nd], o[sub][mi][nd], 0, 0, 0);
      }
      __builtin_amdgcn_s_setprio(0);
    }
    __syncthreads();
    cur ^= 1;
  }

  short* xb = x + ((size_t)b * 1024) * 1024 + (bh & 15) * 64;
#pragma unroll
  for (int sub = 0; sub < 2; ++sub)
#pragma unroll
    for (int mi = 0; mi < 2; ++mi)
#pragma unroll
      for (int j = 0; j < 4; ++j) {
        float rs = psum[sub][mi][j];
#pragma unroll
        for (int dd = 1; dd < 16; dd <<= 1) rs += __shfl_xor(rs, dd, 64);
        float inv = rs > 0.f ? 1.0f / rs : 0.f;
        int qg = qp * 256 + sub * 128 + w * 32 + mi * 16 + lg * 4 + j;
#pragma unroll
        for (int nd = 0; nd < 4; ++nd) {
          int d = nd * 16 + lr;
          xb[(size_t)qg * 1024 + d] = f2bf(o[sub][mi][nd][j] * inv);
        }
      }
}

extern "C" void kernel_launch(void* const* d_in, const int* in_sizes, int n_in,
                              void* d_out, int out_size, void* d_ws, size_t ws_size,
                              hipStream_t stream) {
  const float* q = (const float*)d_in[0];
  const float* k = (const float*)d_in[1];
  const float* v = (const float*)d_in[2];
  const int* mask = (const int*)d_in[3];
  const int* tmask = (const int*)d_in[4];
  const float* Wq = (const float*)d_in[5];
  const float* Wk = (const float*)d_in[6];
  const float* Wv = (const float*)d_in[7];
  const float* Wo = (const float*)d_in[8];
  const float* bo = (const float*)d_in[9];
  float* out = (float*)d_out;

  char* ws = (char*)d_ws;
  const size_t MB = 1u << 20;
  if (ws_size < 73 * MB) return;
  short* WtAll = (short*)(ws + 0 * MB);   // Wqt,Wkt,Wvt,Wot contiguous (8 MB)
  short* qh  = (short*)(ws + 8 * MB);
  short* kh  = (short*)(ws + 24 * MB);
  short* vh  = (short*)(ws + 40 * MB);
  short* vht = (short*)(ws + 56 * MB);
  u64*   pkb = (u64*)(ws + 72 * MB);      // 1 MB packed masks
  short* x   = (short*)(ws + 40 * MB);    // aliases vh (dead after vtrans)
  // qb/kb live in d_out (32 MB, overwritten by gemm_out at the very end);
  // vb aliases the vht region (vht written only later, by vtrans).
  short* qbA = (short*)d_out;
  short* kbA = (short*)d_out + 8 * 1024 * 1024;
  short* vbA = (short*)(ws + 56 * MB);

  prologue<<<dim3(21504), 256, 0, stream>>>(q, k, v, qbA, kbA, vbA,
                                            Wq, Wk, Wv, Wo, WtAll,
                                            mask, tmask, pkb);
  gemm_qkv<<<dim3(8, 96), 512, 0, stream>>>(qbA, kbA, vbA, WtAll, qh, kh, vh);
  vtrans<<<dim3(16, 128), 256, 0, stream>>>(vh, vht);
  attn<<<dim3(8, 64), 256, 0, stream>>>(qh, kh, vht, pkb, x);
  gemm_out<<<dim3(8, 32), 512, 0, stream>>>(x, WtAll + 3 * 1024 * 1024, bo, out);
}